// Round 1
// baseline (114.941 us; speedup 1.0000x reference)
//
#include <hip/hip_runtime.h>
#include <math.h>

#define NPTS_QPB 64      // queries per block
#define NPTS_CHUNKS 8    // j-chunks (waves) per block
#define MAIN_BLOCK (NPTS_QPB * NPTS_CHUNKS)  // 512 threads
#define BIGV 1e10f
#define EPSV 1e-8f

// kernel 1: sq[i] = round(x*x) + round(y*y)  (matches np.sum(pc*pc, axis=1))
__global__ void esdf_sq_kernel(const float2* __restrict__ pc,
                               float* __restrict__ sq, int n) {
#pragma clang fp contract(off)
    int i = blockIdx.x * blockDim.x + threadIdx.x;
    if (i < n) {
        float2 p = pc[i];
        float xx = p.x * p.x;
        float yy = p.y * p.y;
        sq[i] = xx + yy;
    }
}

// kernel 2: per-row argmin of d2 = max(sq_i + sq_j - 2*dot(i,j), 0), j != i,
// then esdf/gradient epilogue.
__global__ __launch_bounds__(MAIN_BLOCK)
void esdf_nn_kernel(const float2* __restrict__ pc,
                    const float* __restrict__ sq,
                    float* __restrict__ out, int n) {
#pragma clang fp contract(off)
    const int lane  = threadIdx.x & 63;
    // wave-uniform chunk id; readfirstlane so the compiler knows it's uniform
    const int chunk = __builtin_amdgcn_readfirstlane((int)(threadIdx.x >> 6));
    const int qbase = blockIdx.x * NPTS_QPB;
    const int i     = qbase + lane;

    const float2 pi  = pc[i];
    const float  sqi = sq[i];
    const float  xi  = pi.x, yi = pi.y;

    const int JC     = n / NPTS_CHUNKS;   // 2048
    const int j0base = chunk * JC;

    float best0 = BIGV, best1 = BIGV;
    int   bi0 = 0, bi1 = 1;

    const float4* pc4 = (const float4*)pc;  // pc4[k] holds points 2k, 2k+1
    const float4* sq4 = (const float4*)sq;

    for (int jt = 0; jt < JC; jt += 8) {
        const int j0 = j0base + jt;       // wave-uniform
        float4 p01 = pc4[(j0 >> 1) + 0];
        float4 p23 = pc4[(j0 >> 1) + 1];
        float4 p45 = pc4[(j0 >> 1) + 2];
        float4 p67 = pc4[(j0 >> 1) + 3];
        float4 sA  = sq4[(j0 >> 2) + 0];
        float4 sB  = sq4[(j0 >> 2) + 1];
        float xs[8] = {p01.x, p01.z, p23.x, p23.z, p45.x, p45.z, p67.x, p67.z};
        float ys[8] = {p01.y, p01.w, p23.y, p23.w, p45.y, p45.w, p67.y, p67.w};
        float ss[8] = {sA.x, sA.y, sA.z, sA.w, sB.x, sB.y, sB.z, sB.w};

        // wave-uniform: does [j0, j0+8) intersect this block's query range?
        const bool safe = (j0 + 8 <= qbase) || (j0 >= qbase + NPTS_QPB);
        if (safe) {
#pragma unroll
            for (int k = 0; k < 8; ++k) {
                float dot = fmaf(ys[k], yi, xs[k] * xi);   // BLAS fma order
                float s   = sqi + ss[k];
                float d2  = fmaf(-2.0f, dot, s);
                d2 = fmaxf(d2, 0.0f);
                if (k & 1) { if (d2 < best1) { best1 = d2; bi1 = j0 + k; } }
                else       { if (d2 < best0) { best0 = d2; bi0 = j0 + k; } }
            }
        } else {
#pragma unroll
            for (int k = 0; k < 8; ++k) {
                float dot = fmaf(ys[k], yi, xs[k] * xi);
                float s   = sqi + ss[k];
                float d2  = fmaf(-2.0f, dot, s);
                d2 = fmaxf(d2, 0.0f);
                bool ok = (j0 + k) != i;   // exclude diagonal (ref adds BIG)
                if (k & 1) { if (ok && d2 < best1) { best1 = d2; bi1 = j0 + k; } }
                else       { if (ok && d2 < best0) { best0 = d2; bi0 = j0 + k; } }
            }
        }
    }

    // merge the two interleaved accumulators (tie -> smaller index = numpy argmin)
    float best; int bi;
    if (best0 < best1 || (best0 == best1 && bi0 < bi1)) { best = best0; bi = bi0; }
    else                                                 { best = best1; bi = bi1; }

    __shared__ float sbest[NPTS_CHUNKS][NPTS_QPB];
    __shared__ int   sbidx[NPTS_CHUNKS][NPTS_QPB];
    sbest[chunk][lane] = best;
    sbidx[chunk][lane] = bi;
    __syncthreads();

    if (threadIdx.x < NPTS_QPB) {
        const int q = threadIdx.x;
        float b = sbest[0][q]; int ix = sbidx[0][q];
#pragma unroll
        for (int c = 1; c < NPTS_CHUNKS; ++c) {
            float bb = sbest[c][q]; int jj = sbidx[c][q];
            if (bb < b || (bb == b && jj < ix)) { b = bb; ix = jj; }
        }
        const int gq = qbase + q;
        float esdf = sqrtf(b);
        float2 pn = pc[ix];
        float2 pq = pc[gq];
        float dx = pq.x - pn.x;
        float dy = pq.y - pn.y;
        float a = dx * dx;
        float c2 = dy * dy;
        float nrm = sqrtf(a + c2);
        float inv = nrm + EPSV;
        float gx = dx / inv;
        float gy = dy / inv;
        // out = mu(4,N) then lam(3,N), flat
        out[0 * n + gq] = gx;
        out[1 * n + gq] = -gx;
        out[2 * n + gq] = gy;
        out[3 * n + gq] = -gy;
        out[4 * n + gq] = gx;
        out[5 * n + gq] = gy;
        out[6 * n + gq] = esdf / 10.0f;
    }
}

extern "C" void kernel_launch(void* const* d_in, const int* in_sizes, int n_in,
                              void* d_out, int out_size, void* d_ws, size_t ws_size,
                              hipStream_t stream) {
    const float2* pc = (const float2*)d_in[0];
    float* out = (float*)d_out;
    float* sq  = (float*)d_ws;           // n floats of scratch
    const int n = in_sizes[0] / 2;       // 16384

    esdf_sq_kernel<<<(n + 255) / 256, 256, 0, stream>>>(pc, sq, n);
    esdf_nn_kernel<<<n / NPTS_QPB, MAIN_BLOCK, 0, stream>>>(pc, sq, out, n);
}

// Round 2
// 71.277 us; speedup vs baseline: 1.6126x; 1.6126x over previous
//
#include <hip/hip_runtime.h>
#include <math.h>

#define QPB 64           // queries per block
#define CHUNKS 8         // j-chunks (waves) per block
#define MAIN_BLOCK (QPB * CHUNKS)   // 512 threads
#define JPART 4          // j-partitions across blocks (occupancy lever)
#define BIGV 1e10f
#define EPSV 1e-8f

// kernel 1: sq[i] = x*x + y*y  (matches np.sum(pc*pc, axis=1) rounding)
__global__ void esdf_sq_kernel(const float2* __restrict__ pc,
                               float* __restrict__ sq, int n) {
#pragma clang fp contract(off)
    int i = blockIdx.x * blockDim.x + threadIdx.x;
    if (i < n) {
        float2 p = pc[i];
        float xx = p.x * p.x;
        float yy = p.y * p.y;
        sq[i] = xx + yy;
    }
}

// kernel 2: partial per-row argmin of d2 = max(sq_i + sq_j - 2*dot(i,j), 0),
// j != i, over this block's j-partition. Writes (best, idx) partials.
__global__ __launch_bounds__(MAIN_BLOCK)
void esdf_nn_partial(const float2* __restrict__ pc,
                     const float* __restrict__ sq,
                     float* __restrict__ pbest,
                     int* __restrict__ pidx, int n) {
#pragma clang fp contract(off)
    const int lane  = threadIdx.x & 63;
    const int chunk = __builtin_amdgcn_readfirstlane((int)(threadIdx.x >> 6));
    const int qblk  = blockIdx.x >> 2;        // 256 query blocks
    const int jpart = blockIdx.x & (JPART - 1);
    const int qbase = qblk * QPB;
    const int i     = qbase + lane;

    const float2 pi  = pc[i];
    const float  sqi = sq[i];
    const float  xi  = pi.x, yi = pi.y;

    const int JC     = n / (JPART * CHUNKS);  // 512 j's per wave
    const int j0base = jpart * (n / JPART) + chunk * JC;

    float best0 = BIGV, best1 = BIGV;
    int   bi0 = 0, bi1 = 1;

    const float4* pc4 = (const float4*)pc;    // pc4[k] holds points 2k, 2k+1
    const float4* sq4 = (const float4*)sq;

    for (int jt = 0; jt < JC; jt += 8) {
        const int j0 = j0base + jt;           // wave-uniform
        float4 p01 = pc4[(j0 >> 1) + 0];
        float4 p23 = pc4[(j0 >> 1) + 1];
        float4 p45 = pc4[(j0 >> 1) + 2];
        float4 p67 = pc4[(j0 >> 1) + 3];
        float4 sA  = sq4[(j0 >> 2) + 0];
        float4 sB  = sq4[(j0 >> 2) + 1];
        float xs[8] = {p01.x, p01.z, p23.x, p23.z, p45.x, p45.z, p67.x, p67.z};
        float ys[8] = {p01.y, p01.w, p23.y, p23.w, p45.y, p45.w, p67.y, p67.w};
        float ss[8] = {sA.x, sA.y, sA.z, sA.w, sB.x, sB.y, sB.z, sB.w};

        // wave-uniform: does [j0, j0+8) intersect this block's query range?
        const bool safe = (j0 + 8 <= qbase) || (j0 >= qbase + QPB);
        if (safe) {
#pragma unroll
            for (int k = 0; k < 8; ++k) {
                float dot = fmaf(ys[k], yi, xs[k] * xi);   // BLAS fma order
                float s   = sqi + ss[k];
                float d2  = fmaf(-2.0f, dot, s);
                d2 = fmaxf(d2, 0.0f);
                if (k & 1) { if (d2 < best1) { best1 = d2; bi1 = j0 + k; } }
                else       { if (d2 < best0) { best0 = d2; bi0 = j0 + k; } }
            }
        } else {
#pragma unroll
            for (int k = 0; k < 8; ++k) {
                float dot = fmaf(ys[k], yi, xs[k] * xi);
                float s   = sqi + ss[k];
                float d2  = fmaf(-2.0f, dot, s);
                d2 = fmaxf(d2, 0.0f);
                bool ok = (j0 + k) != i;      // exclude diagonal (ref adds BIG)
                if (k & 1) { if (ok && d2 < best1) { best1 = d2; bi1 = j0 + k; } }
                else       { if (ok && d2 < best0) { best0 = d2; bi0 = j0 + k; } }
            }
        }
    }

    // merge interleaved accumulators (tie -> smaller index = numpy argmin)
    float best; int bi;
    if (best0 < best1 || (best0 == best1 && bi0 < bi1)) { best = best0; bi = bi0; }
    else                                                 { best = best1; bi = bi1; }

    __shared__ float sbest[CHUNKS][QPB];
    __shared__ int   sbidx[CHUNKS][QPB];
    sbest[chunk][lane] = best;
    sbidx[chunk][lane] = bi;
    __syncthreads();

    if (threadIdx.x < QPB) {
        const int q = threadIdx.x;
        float b = sbest[0][q]; int ix = sbidx[0][q];
#pragma unroll
        for (int c = 1; c < CHUNKS; ++c) {
            float bb = sbest[c][q]; int jj = sbidx[c][q];
            if (bb < b || (bb == b && jj < ix)) { b = bb; ix = jj; }
        }
        pbest[jpart * n + qbase + q] = b;
        pidx [jpart * n + qbase + q] = ix;
    }
}

// kernel 3: reduce JPART partials per query + epilogue
__global__ void esdf_finalize(const float2* __restrict__ pc,
                              const float* __restrict__ pbest,
                              const int* __restrict__ pidx,
                              float* __restrict__ out, int n) {
#pragma clang fp contract(off)
    int q = blockIdx.x * blockDim.x + threadIdx.x;
    if (q >= n) return;
    float b = pbest[q]; int ix = pidx[q];
#pragma unroll
    for (int p = 1; p < JPART; ++p) {
        float bb = pbest[p * n + q];
        int   jj = pidx [p * n + q];
        if (bb < b || (bb == b && jj < ix)) { b = bb; ix = jj; }
    }
    float esdf = sqrtf(b);
    float2 pn = pc[ix];
    float2 pq = pc[q];
    float dx = pq.x - pn.x;
    float dy = pq.y - pn.y;
    float a  = dx * dx;
    float c2 = dy * dy;
    float nrm = sqrtf(a + c2);
    float inv = nrm + EPSV;
    float gx = dx / inv;
    float gy = dy / inv;
    // out = mu(4,N) then lam(3,N), flat
    out[0 * n + q] = gx;
    out[1 * n + q] = -gx;
    out[2 * n + q] = gy;
    out[3 * n + q] = -gy;
    out[4 * n + q] = gx;
    out[5 * n + q] = gy;
    out[6 * n + q] = esdf / 10.0f;
}

extern "C" void kernel_launch(void* const* d_in, const int* in_sizes, int n_in,
                              void* d_out, int out_size, void* d_ws, size_t ws_size,
                              hipStream_t stream) {
    const float2* pc = (const float2*)d_in[0];
    float* out = (float*)d_out;
    const int n = in_sizes[0] / 2;            // 16384

    // ws layout: sq[n] | pbest[JPART*n] | pidx[JPART*n]  (~576 KB)
    float* sq    = (float*)d_ws;
    float* pbest = sq + n;
    int*   pidx  = (int*)(pbest + JPART * n);

    esdf_sq_kernel<<<(n + 255) / 256, 256, 0, stream>>>(pc, sq, n);
    esdf_nn_partial<<<(n / QPB) * JPART, MAIN_BLOCK, 0, stream>>>(pc, sq, pbest, pidx, n);
    esdf_finalize<<<(n + 255) / 256, 256, 0, stream>>>(pc, pbest, pidx, out, n);
}